// Round 2
// baseline (9.883 us; speedup 1.0000x reference)
//
#include <hip/hip_runtime.h>
#include <hip/hip_bf16.h>

// out[b, j] = tokens[b, idx[b, j], j]
// tokens: [B=64, S=512, E=1024] fp32,  idx: [B, E] int32,  out: [B, E] fp32
// Hardcoded shape => all address math is shifts/masks.
//
// 4 elements per thread: one int4 idx load, 4 independent scattered gathers
// (ILP-driven memory-level parallelism), one float4 store.
// Grid: 256 blocks x 64 threads = 16384 threads x 4 elem = 65536 elements.
// One wave per CU across all 256 CUs; each wave keeps 64x4 = 256 scattered
// requests in flight.

__global__ void __launch_bounds__(64)
embrace_gather_kernel(const float* __restrict__ tokens,
                      const int* __restrict__ idx,
                      float* __restrict__ out) {
    // flat vector index over [B*E/4)
    int v = blockIdx.x * 64 + threadIdx.x;     // 0 .. 16383
    int base = v << 2;                         // first element index, 16B aligned

    int b = base >> 10;                        // E = 1024
    int j = base & 1023;                       // j of element 0 (j..j+3 same b)

    int4 s4 = *reinterpret_cast<const int4*>(idx + base);   // coalesced 16B

    // tokens element offset: (b*512 + s) * 1024 + j  == ((b<<9)+s)<<10 | j
    const size_t brow = (size_t)b << 19;       // b * S * E = b * 524288

    float4 r;
    r.x = tokens[brow + ((size_t)s4.x << 10) + (j + 0)];
    r.y = tokens[brow + ((size_t)s4.y << 10) + (j + 1)];
    r.z = tokens[brow + ((size_t)s4.z << 10) + (j + 2)];
    r.w = tokens[brow + ((size_t)s4.w << 10) + (j + 3)];

    *reinterpret_cast<float4*>(out + base) = r;            // coalesced 16B
}

extern "C" void kernel_launch(void* const* d_in, const int* in_sizes, int n_in,
                              void* d_out, int out_size, void* d_ws, size_t ws_size,
                              hipStream_t stream) {
    const float* tokens = (const float*)d_in[0];   // [B, S, E]
    const int*   idx    = (const int*)d_in[1];     // [B, E]
    float*       out    = (float*)d_out;           // [B, E]

    // out_size = 65536 = B*E; 4 elem/thread, 64 threads/block
    const int threads = out_size >> 2;             // 16384
    const int block   = 64;
    const int grid    = threads / block;           // 256
    embrace_gather_kernel<<<grid, block, 0, stream>>>(tokens, idx, out);
}